// Round 15
// baseline (543.756 us; speedup 1.0000x reference)
//
#include <hip/hip_runtime.h>
#include <math.h>

// Problem constants (G=1024 grid, known structure)
#define GSZ   1024
#define NV    (GSZ*GSZ)           // 1048576 vertices
#define N3    (NV*3)              // floats per [NV,3] array
#define FH    ((GSZ-1)*(GSZ-1))   // faces in first half
#define NF    (2*FH)              // total faces
#define O1    N3                  // centroid offset in d_out (floats)
#define O2    (O1 + 3*NF)         // fn offset
#define O3    (O2 + 3*NF)         // vn offset
#define LAM   10.0f

// Product-form Chebyshev: 64 Richardson steps, roots of the degree-64
// Chebyshev polynomial on lambda(M)=[1,91] (validated r7-r13), LF order.
// Schedule (r13-proven): first(s3,reg) + 19 x s3(LDS tile) + s4(reg) = 64.
#define CH_THETA 46.0
#define CH_DELTA 45.0
#define NSTEP 64

#define NTHR 256
#define LDSW 526                  // LDS row stride (cols): data at 4..523, pads 3/524

typedef float f4u __attribute__((ext_vector_type(4), aligned(4)));

__device__ __forceinline__ void diag4(int i, int t, float dg[4]) {
  bool im = (i > 0), ip = (i < GSZ - 1);
#pragma unroll
  for (int k = 0; k < 4; ++k) {
    bool jm = (k > 0) || (t > 0);
    bool jp = (k < 3) || (t < 255);
    int deg = (int)jm + (int)jp + (int)im + (int)ip
            + (int)(ip && jm) + (int)(im && jp);
    dg[k] = 1.0f + LAM * (float)deg;
  }
}

// q = (A x)_row (register version, validated r8-r14)
__device__ __forceinline__ void sten_q4(
    const float* up, const float* mid, const float* dn,
    float Lm, float Ld, float Rm, float Ru,
    int r, int t2, float q[4]) {
  bool im = (r > 0), ip = (r < GSZ - 1);
  bool jm = (t2 > 0), jp = (t2 < 255);
  float u0 = im ? up[0] : 0.f, u1 = im ? up[1] : 0.f;
  float u2 = im ? up[2] : 0.f, u3 = im ? up[3] : 0.f;
  float d0 = ip ? dn[0] : 0.f, d1 = ip ? dn[1] : 0.f;
  float d2 = ip ? dn[2] : 0.f, d3 = ip ? dn[3] : 0.f;
  float lm = jm ? Lm : 0.f, ld = (jm && ip) ? Ld : 0.f;
  float rm = jp ? Rm : 0.f, ru = (jp && im) ? Ru : 0.f;
  float dg[4]; diag4(r, t2, dg);
  q[0] = dg[0]*mid[0] - LAM*(lm     + mid[1] + u0 + d0 + ld + u1);
  q[1] = dg[1]*mid[1] - LAM*(mid[0] + mid[2] + u1 + d1 + d0 + u2);
  q[2] = dg[2]*mid[2] - LAM*(mid[1] + mid[3] + u2 + d2 + d1 + u3);
  q[3] = dg[3]*mid[3] - LAM*(mid[2] + rm     + u3 + d3 + d2 + ru);
}

// LDS variant: 4 cells at lds col c (aligned), grid row grow, grid col gc0.
// Summation order identical to sten_q4 -> bitwise-same results.
__device__ __forceinline__ void sten_lds4(
    const float* __restrict__ up, const float* __restrict__ md,
    const float* __restrict__ dn, int c, int grow, int gc0, float q[4]) {
  bool im = (grow > 0), ip = (grow < GSZ - 1);
  float u[4], d[4], m[4];
#pragma unroll
  for (int k = 0; k < 4; ++k) { u[k]=up[c+k]; d[k]=dn[c+k]; m[k]=md[c+k]; }
  float mL = md[c-1], mR = md[c+4];
  float uR = up[c+4], dL = dn[c-1];
#pragma unroll
  for (int k = 0; k < 4; ++k) {
    int gc = gc0 + k;
    bool jm = (gc > 0), jp = (gc < GSZ - 1);
    float lm = jm ? (k==0 ? mL : m[k-1]) : 0.f;
    float rm = jp ? (k==3 ? mR : m[k+1]) : 0.f;
    float uu = im ? u[k] : 0.f;
    float dd = ip ? d[k] : 0.f;
    float ld = (jm && ip) ? (k==0 ? dL : d[k-1]) : 0.f;
    float ru = (jp && im) ? (k==3 ? uR : u[k+1]) : 0.f;
    int deg = (int)jm + (int)jp + (int)im + (int)ip
            + (int)(ip && jm) + (int)(im && jp);
    float dg = 1.0f + LAM * (float)deg;
    q[k] = dg * m[k] - LAM * (lm + rm + uu + dd + ld + ru);
  }
}

// interleaved u -> one color's float4 at vtx..vtx+3
__device__ __forceinline__ float4 load_u_col(const float* __restrict__ u,
                                             int vtx, int col) {
  float4 a = *(const float4*)(u + 3 * vtx);
  float4 b = *(const float4*)(u + 3 * vtx + 4);
  float4 c = *(const float4*)(u + 3 * vtx + 8);
  if (col == 0) return make_float4(a.x, a.w, b.z, c.y);
  if (col == 1) return make_float4(a.y, b.x, b.w, c.z);
  return make_float4(a.z, b.y, c.x, c.w);
}

// Register-tile level macro (validated r12-r13) for first/last kernels.
#define DO_LEVEL(LEV, LO, HI, OM, OFF)                                      \
  {                                                                         \
    if (lane == 0) {                                                        \
      _Pragma("unroll") for (int tr = (LO)-1; tr <= (HI)+1; ++tr)           \
        e0[LEV][wv][tr] = X[tr][0];                                         \
    }                                                                       \
    if (lane == 63) {                                                       \
      _Pragma("unroll") for (int tr = (LO)-1; tr <= (HI)+1; ++tr)           \
        e3[LEV][wv][tr] = X[tr][3];                                         \
    }                                                                       \
    __syncthreads();                                                        \
    float XL[12], XR[12];                                                   \
    _Pragma("unroll") for (int tr = (LO)-1; tr <= (HI)+1; ++tr) {           \
      XR[tr] = __shfl_down(X[tr][0], 1, 64);                                \
      XL[tr] = __shfl_up(X[tr][3], 1, 64);                                  \
    }                                                                       \
    if (lane == 63) {                                                       \
      _Pragma("unroll") for (int tr = (LO)-1; tr <= (HI)+1; ++tr)           \
        XR[tr] = (t2 < 255) ? e0[LEV][wv + 1][tr] : 0.f;                    \
    }                                                                       \
    if (lane == 0) {                                                        \
      _Pragma("unroll") for (int tr = (LO)-1; tr <= (HI)+1; ++tr)           \
        XL[tr] = (t2 > 0) ? e3[LEV][wv - 1][tr] : 0.f;                      \
    }                                                                       \
    float pm0 = X[(LO)-1][0], pm1 = X[(LO)-1][1],                           \
          pm2 = X[(LO)-1][2], pm3 = X[(LO)-1][3];                           \
    _Pragma("unroll") for (int tr = (LO); tr <= (HI); ++tr) {               \
      int r = r0 - (OFF) + tr;                                              \
      float pm[4] = { pm0, pm1, pm2, pm3 };                                 \
      float q[4];                                                           \
      sten_q4(pm, X[tr], X[tr+1], XL[tr], XL[tr+1], XR[tr], XR[tr-1],       \
              r, t2, q);                                                    \
      pm0 = X[tr][0]; pm1 = X[tr][1]; pm2 = X[tr][2]; pm3 = X[tr][3];       \
      _Pragma("unroll") for (int k = 0; k < 4; ++k)                         \
        X[tr][k] += (OM) * (BB[tr-1][k] - q[k]);                            \
    }                                                                       \
  }

// ================= LDS-tiled fused 3-step (steady state) =================
// R=8 out rows x C=512 cols per block; 768 blocks (8 XCD x 16 rtile x
// 2 ctile x 3 colors); 2 blocks/CU (LDS 78 KB). Traffic 4.28 plane-sets.
__global__ __launch_bounds__(256, 2) void k_rich3_lds(
    const float* __restrict__ xin, float* __restrict__ xout,
    const float* __restrict__ bpl,
    float w0, float w1, float w2) {
  int b = blockIdx.x;
  int xcd  = b & 7;
  int rest = b >> 3;                 // 0..95
  int col  = rest / 32;              // color 0..2
  int r2   = rest - col * 32;        // 0..31
  int tile_c = r2 & 1;
  int kk   = r2 >> 1;                // 0..15
  int r0 = (xcd << 7) + (kk << 3);   // output rows [r0, r0+8)
  int c0 = tile_c << 9;              // output cols [c0, c0+512)
  int t2 = threadIdx.x;

  const float* XS = xin + col * NV;
  const float* BP = bpl + col * NV;
  float* XO = xout + col * NV;

  __shared__ float XOs[14][LDSW];    // x old: rows r0-3..r0+10 at ldsc 4..523
  __shared__ float XNs[12][LDSW];    // x new: rows r0-2..r0+9  (idx rr-1)
  __shared__ float Bs [12][LDSW];    // b: rows r0-2..r0+9 (idx rr-1)

  // zero the pad cols that levels read (c-1 at c=4 -> col 3; c+4 at c=520 -> col 524)
  for (int idx = t2; idx < 26 * 2; idx += 256) {
    int rr = idx >> 1, c = (idx & 1) ? 524 : 3;
    if (rr < 14) XOs[rr][c] = 0.f; else XNs[rr - 14][c] = 0.f;
  }
  // fill x old: 14 rows x 130 float4 groups (ldsc 4..523 = gcol c0-4..c0+515)
  for (int idx = t2; idx < 14 * 130; idx += 256) {
    int rr = idx / 130, g = idx - rr * 130;
    int grow = r0 - 3 + rr;
    int gc = c0 - 4 + (g << 2);
    float4 v = make_float4(0.f, 0.f, 0.f, 0.f);
    if (grow >= 0 && grow < GSZ && gc >= 0 && gc <= GSZ - 4)
      v = *(const float4*)(XS + grow * GSZ + gc);
    *(float4*)&XOs[rr][4 + (g << 2)] = v;
  }
  // fill b: rows rr 1..12 (idx rw=rr-1)
  for (int idx = t2; idx < 12 * 130; idx += 256) {
    int rw = idx / 130, g = idx - rw * 130;
    int grow = r0 - 2 + rw;
    int gc = c0 - 4 + (g << 2);
    float4 v = make_float4(0.f, 0.f, 0.f, 0.f);
    if (grow >= 0 && grow < GSZ && gc >= 0 && gc <= GSZ - 4)
      v = *(const float4*)(BP + grow * GSZ + gc);
    *(float4*)&Bs[rw][4 + (g << 2)] = v;
  }
  __syncthreads();

  // ---- level 0: rows rr 1..12, groups c = 4..520 ----
  for (int idx = t2; idx < 12 * 130; idx += 256) {
    int rw = idx / 130, g = idx - rw * 130;
    int rr = rw + 1;
    int c = 4 + (g << 2);
    int grow = r0 - 3 + rr;
    int gc0 = c0 - 8 + c;
    float q[4];
    sten_lds4(XOs[rr-1], XOs[rr], XOs[rr+1], c, grow, gc0, q);
    float4 b4 = *(float4*)&Bs[rr-1][c];
    float o0 = XOs[rr][c]   + w0 * (b4.x - q[0]);
    float o1 = XOs[rr][c+1] + w0 * (b4.y - q[1]);
    float o2 = XOs[rr][c+2] + w0 * (b4.z - q[2]);
    float o3 = XOs[rr][c+3] + w0 * (b4.w - q[3]);
    *(float4*)&XNs[rr-1][c] = make_float4(o0, o1, o2, o3);
  }
  __syncthreads();

  // ---- level 1: rows rr 2..11, groups c = 4..520; writes back to XOs ----
  for (int idx = t2; idx < 10 * 130; idx += 256) {
    int rw = idx / 130, g = idx - rw * 130;
    int rr = rw + 2;
    int c = 4 + (g << 2);
    int grow = r0 - 3 + rr;
    int gc0 = c0 - 8 + c;
    float q[4];
    sten_lds4(XNs[rr-2], XNs[rr-1], XNs[rr], c, grow, gc0, q);
    float4 b4 = *(float4*)&Bs[rr-1][c];
    float o0 = XNs[rr-1][c]   + w1 * (b4.x - q[0]);
    float o1 = XNs[rr-1][c+1] + w1 * (b4.y - q[1]);
    float o2 = XNs[rr-1][c+2] + w1 * (b4.z - q[2]);
    float o3 = XNs[rr-1][c+3] + w1 * (b4.w - q[3]);
    *(float4*)&XOs[rr][c] = make_float4(o0, o1, o2, o3);
  }
  __syncthreads();

  // ---- level 2: rows rr 3..10 (grid r0..r0+7), cols c 8..516+3, store global ----
  for (int idx = t2; idx < 8 * 128; idx += 256) {
    int rw = idx >> 7, g = idx & 127;
    int rr = rw + 3;
    int c = 8 + (g << 2);
    int grow = r0 + rw;
    int gc0 = c0 + (g << 2);
    float q[4];
    sten_lds4(XOs[rr-1], XOs[rr], XOs[rr+1], c, grow, gc0, q);
    float4 b4 = *(float4*)&Bs[rr-1][c];
    float o0 = XOs[rr][c]   + w2 * (b4.x - q[0]);
    float o1 = XOs[rr][c+1] + w2 * (b4.y - q[1]);
    float o2 = XOs[rr][c+2] + w2 * (b4.z - q[2]);
    float o3 = XOs[rr][c+3] + w2 * (b4.w - q[3]);
    *(float4*)(XO + grow * GSZ + gc0) = make_float4(o0, o1, o2, o3);
  }
}

// ---------- first launch (register tile, validated r13): x0=0, x1=b/theta ----------
__global__ __launch_bounds__(256, 3) void k_rich3_first(
    const float* __restrict__ u, float* __restrict__ xout,
    float* __restrict__ bpl,
    float w0, float w1, float w2) {
  int tile = blockIdx.x & 255;
  int col  = blockIdx.x >> 8;
  int t2 = threadIdx.x;
  int lane = t2 & 63;
  int wv = t2 >> 6;
  int r0 = ((tile & 7) << 7) + ((tile >> 3) << 2);
  int j0 = t2 << 2;

  float* BPo = bpl + col * NV;
  float* XO  = xout + col * NV;

  __shared__ float e0[3][4][12], e3[3][4][12];

  float X[10][4];
#pragma unroll
  for (int tr = 0; tr < 10; ++tr) {
    X[tr][0]=0.f; X[tr][1]=0.f; X[tr][2]=0.f; X[tr][3]=0.f;
  }
  float BB[8][4];
#pragma unroll
  for (int tr = 1; tr <= 8; ++tr) {
    int r = r0 - 3 + tr;
    float4 v = (r >= 0 && r < GSZ) ? load_u_col(u, r * GSZ + j0, col)
                                   : make_float4(0.f, 0.f, 0.f, 0.f);
    BB[tr-1][0]=v.x; BB[tr-1][1]=v.y; BB[tr-1][2]=v.z; BB[tr-1][3]=v.w;
    if (tr >= 3 && tr <= 6)
      *(float4*)(BPo + r * GSZ + j0) = v;
  }

  DO_LEVEL(0, 1, 8, w0, 3)
  DO_LEVEL(1, 2, 7, w1, 3)
  DO_LEVEL(2, 3, 6, w2, 3)

#pragma unroll
  for (int tr = 3; tr <= 6; ++tr) {
    int r = r0 - 3 + tr;
    *(float4*)(XO + r * GSZ + j0) = make_float4(X[tr][0], X[tr][1], X[tr][2], X[tr][3]);
  }
}

// ---------- final fused 4-step (register tile, validated r12/r13) ----------
__global__ __launch_bounds__(256, 3) void k_rich4(
    const float* __restrict__ xin, float* __restrict__ xout,
    const float* __restrict__ bpl,
    float w0, float w1, float w2, float w3) {
  int tile = blockIdx.x & 255;
  int col  = blockIdx.x >> 8;
  int t2 = threadIdx.x;
  int lane = t2 & 63;
  int wv = t2 >> 6;
  int r0 = ((tile & 7) << 7) + ((tile >> 3) << 2);
  int j0 = t2 << 2;

  const float* XS = xin + col * NV;
  const float* BP = bpl + col * NV;
  float* XO = xout + col * NV;

  __shared__ float e0[4][4][12], e3[4][4][12];

  float X[12][4];
#pragma unroll
  for (int tr = 0; tr < 12; ++tr) {
    int r = r0 - 4 + tr;
    if (r >= 0 && r < GSZ) {
      float4 v = *(const float4*)(XS + r * GSZ + j0);
      X[tr][0]=v.x; X[tr][1]=v.y; X[tr][2]=v.z; X[tr][3]=v.w;
    } else { X[tr][0]=0.f; X[tr][1]=0.f; X[tr][2]=0.f; X[tr][3]=0.f; }
  }
  float BB[10][4];
#pragma unroll
  for (int tr = 1; tr <= 10; ++tr) {
    int r = r0 - 4 + tr;
    if (r >= 0 && r < GSZ) {
      float4 v = *(const float4*)(BP + r * GSZ + j0);
      BB[tr-1][0]=v.x; BB[tr-1][1]=v.y; BB[tr-1][2]=v.z; BB[tr-1][3]=v.w;
    } else { BB[tr-1][0]=0.f; BB[tr-1][1]=0.f; BB[tr-1][2]=0.f; BB[tr-1][3]=0.f; }
  }

  DO_LEVEL(0, 1, 10, w0, 4)
  DO_LEVEL(1, 2,  9, w1, 4)
  DO_LEVEL(2, 3,  8, w2, 4)
  DO_LEVEL(3, 4,  7, w3, 4)

#pragma unroll
  for (int tr = 4; tr <= 7; ++tr) {
    int r = r0 - 4 + tr;
    *(float4*)(XO + r * GSZ + j0) = make_float4(X[tr][0], X[tr][1], X[tr][2], X[tr][3]);
  }
}

// ---------- faces + verts (validated rounds 10-14) ----------
__device__ __forceinline__ void face_cf(float t0x, float t0y, float t0z,
    float t1x, float t1y, float t1z, float b0x, float b0y, float b0z,
    float* cen, float* fnv) {
  const float third = 1.0f / 3.0f;
  cen[0] = (t0x + t1x + b0x) * third;
  cen[1] = (t0y + t1y + b0y) * third;
  cen[2] = (t0z + t1z + b0z) * third;
  float ax = t1x - t0x, ay = t1y - t0y, az = t1z - t0z;
  float bx = b0x - t0x, by = b0y - t0y, bz = b0z - t0z;
  float cx = ay * bz - az * by;
  float cy = az * bx - ax * bz;
  float cz = ax * by - ay * bx;
  float inv = 1.0f / fmaxf(sqrtf(cx * cx + cy * cy + cz * cz), 1e-12f);
  fnv[0] = cx * inv; fnv[1] = cy * inv; fnv[2] = cz * inv;
}

__global__ __launch_bounds__(NTHR) void k_facesverts(const float* __restrict__ xp,
    float* __restrict__ verts, float* __restrict__ cen, float* __restrict__ fn) {
  int ci = blockIdx.x;           // 0..1022
  int t  = threadIdx.x;
  const float* Ps[3] = { xp, xp + NV, xp + 2 * NV };
  int c0 = t << 2;
  int bT = (ci << 10) + c0, bB = bT + GSZ;
  bool full = (t < 255);
  float T[3][5], B[3][5];
#pragma unroll
  for (int p = 0; p < 3; ++p) {
    float4 a = *(const float4*)(Ps[p] + bT);
    T[p][0] = a.x; T[p][1] = a.y; T[p][2] = a.z; T[p][3] = a.w;
    T[p][4] = full ? Ps[p][bT + 4] : 0.f;
    float4 b = *(const float4*)(Ps[p] + bB);
    B[p][0] = b.x; B[p][1] = b.y; B[p][2] = b.z; B[p][3] = b.w;
    B[p][4] = full ? Ps[p][bB + 4] : 0.f;
  }
  {
    int vtx = bT;
    *(float4*)(verts + 3 * vtx)     = make_float4(T[0][0], T[1][0], T[2][0], T[0][1]);
    *(float4*)(verts + 3 * vtx + 4) = make_float4(T[1][1], T[2][1], T[0][2], T[1][2]);
    *(float4*)(verts + 3 * vtx + 8) = make_float4(T[2][2], T[0][3], T[1][3], T[2][3]);
    if (ci == GSZ - 2) {
      int v2 = bB;
      *(float4*)(verts + 3 * v2)     = make_float4(B[0][0], B[1][0], B[2][0], B[0][1]);
      *(float4*)(verts + 3 * v2 + 4) = make_float4(B[1][1], B[2][1], B[0][2], B[1][2]);
      *(float4*)(verts + 3 * v2 + 8) = make_float4(B[2][2], B[0][3], B[1][3], B[2][3]);
    }
  }
  float c1[12], f1[12], c2[12], f2[12];
#pragma unroll
  for (int k = 0; k < 4; ++k) {
    face_cf(T[0][k], T[1][k], T[2][k], T[0][k+1], T[1][k+1], T[2][k+1],
            B[0][k], B[1][k], B[2][k], &c1[3*k], &f1[3*k]);
    face_cf(T[0][k+1], T[1][k+1], T[2][k+1], B[0][k+1], B[1][k+1], B[2][k+1],
            B[0][k], B[1][k], B[2][k], &c2[3*k], &f2[3*k]);
  }
  size_t fb1 = 3 * ((size_t)ci * (GSZ - 1) + c0);
  size_t fb2 = fb1 + 3 * (size_t)FH;
  if (full) {
#pragma unroll
    for (int w = 0; w < 3; ++w) {
      *(f4u*)(cen + fb1 + 4*w) = (f4u){ c1[4*w], c1[4*w+1], c1[4*w+2], c1[4*w+3] };
      *(f4u*)(fn  + fb1 + 4*w) = (f4u){ f1[4*w], f1[4*w+1], f1[4*w+2], f1[4*w+3] };
      *(f4u*)(cen + fb2 + 4*w) = (f4u){ c2[4*w], c2[4*w+1], c2[4*w+2], c2[4*w+3] };
      *(f4u*)(fn  + fb2 + 4*w) = (f4u){ f2[4*w], f2[4*w+1], f2[4*w+2], f2[4*w+3] };
    }
  } else {
    for (int e = 0; e < 9; ++e) {
      cen[fb1 + e] = c1[e]; fn[fb1 + e] = f1[e];
      cen[fb2 + e] = c2[e]; fn[fb2 + e] = f2[e];
    }
  }
}

// ---------- per-vertex normal ----------
__global__ __launch_bounds__(256) void k_vn(const float* __restrict__ fn,
    float* __restrict__ vn) {
  int t = blockIdx.x * 256 + threadIdx.x;
  int i = t >> 10, j = t & (GSZ - 1);
  float s0 = 0.f, s1 = 0.f, s2 = 0.f;
  bool iN = (i >= 1), iS = (i <= GSZ-2), jW = (j >= 1), jE = (j <= GSZ-2);
  int rowi = i * (GSZ-1);
#define ADD(fidx) { int f_ = (fidx); s0 += fn[3*f_]; s1 += fn[3*f_+1]; s2 += fn[3*f_+2]; }
  if (iS && jE) ADD(rowi + j);
  if (iS && jW) ADD(rowi + j - 1);
  if (iN && jE) ADD(rowi - (GSZ-1) + j);
  if (iS && jW) ADD(FH + rowi + j - 1);
  if (iN && jW) ADD(FH + rowi - (GSZ-1) + j - 1);
  if (iN && jE) ADD(FH + rowi - (GSZ-1) + j);
#undef ADD
  float nrm = sqrtf(s0*s0 + s1*s1 + s2*s2);
  float inv = 1.0f / fmaxf(nrm, 1e-12f);
  vn[3*t] = s0*inv; vn[3*t+1] = s1*inv; vn[3*t+2] = s2*inv;
}

extern "C" void kernel_launch(void* const* d_in, const int* in_sizes, int n_in,
                              void* d_out, int out_size, void* d_ws, size_t ws_size,
                              hipStream_t stream) {
  const float* u = (const float*)d_in[0];
  float* out = (float*)d_out;

  float* verts = out;
  float* cen   = out + O1;
  float* fn    = out + O2;
  float* vn    = out + O3;

  // Scratch: XA = verts region, bpl + XB inside cen/fn region (6NV < 6NF),
  // Dv = vn region (final x; k_vn overwrites last).
  float* XA  = out;
  float* bpl = out + O1;
  float* XB  = out + O1 + 3 * (size_t)NV;
  float* Dv  = out + O3;

  // Lebedev-Finogenov ordering of the 64 Chebyshev roots (doubling).
  int ord[64]; ord[0] = 1;
  for (int m = 1; m < 64; m *= 2) {
    int tmp[128];
    for (int i = 0; i < m; ++i) { tmp[2*i] = ord[i]; tmp[2*i+1] = 4*m - ord[i]; }
    for (int i = 0; i < 2*m; ++i) ord[i] = tmp[i];
  }
  float om[NSTEP];
  for (int j = 0; j < NSTEP; ++j) {
    double r = CH_THETA + CH_DELTA * cos((double)ord[j] * M_PI / (2.0 * NSTEP));
    om[j] = (float)(1.0 / r);
  }

  // 21 launches (r13 schedule): j=0 rich3_first (roots 0..2, register),
  // j=1..19 rich3_lds (roots 3j..3j+2), j=20 rich4 (roots 60..63, register).
  // Parity: j even writes XA, odd writes XB; j=19 wrote XB; j=20 XB -> Dv.
  for (int j = 0; j < 21; ++j) {
    if (j == 0) {
      k_rich3_first<<<dim3(768), dim3(256), 0, stream>>>(u, XA, bpl,
          om[0], om[1], om[2]);
    } else if (j < 20) {
      const float* xin = (j & 1) ? XA : XB;
      float* xout = (j & 1) ? XB : XA;
      k_rich3_lds<<<dim3(768), dim3(256), 0, stream>>>(xin, xout, bpl,
          om[3*j], om[3*j+1], om[3*j+2]);
    } else {
      k_rich4<<<dim3(768), dim3(256), 0, stream>>>(XB, Dv, bpl,
          om[60], om[61], om[62], om[63]);
    }
  }

  k_facesverts<<<dim3(GSZ - 1), dim3(NTHR), 0, stream>>>(Dv, verts, cen, fn);
  k_vn<<<dim3(NV / 256), dim3(256), 0, stream>>>(fn, vn);
}

// Round 16
// 297.495 us; speedup vs baseline: 1.8278x; 1.8278x over previous
//
#include <hip/hip_runtime.h>
#include <math.h>

// Problem constants (G=1024 grid, known structure)
#define GSZ   1024
#define NV    (GSZ*GSZ)           // 1048576 vertices
#define N3    (NV*3)              // floats per [NV,3] array
#define FH    ((GSZ-1)*(GSZ-1))   // faces in first half
#define NF    (2*FH)              // total faces
#define O1    N3                  // centroid offset in d_out (floats)
#define O2    (O1 + 3*NF)         // fn offset
#define O3    (O2 + 3*NF)         // vn offset
#define LAM   10.0f

// Product-form Chebyshev: 64 Richardson steps, roots of the degree-64
// Chebyshev polynomial on lambda(M)=[1,91] (validated r7-r13), LF order.
// Schedule (r13-proven, 304 us): first(s3) + 19 x s3 + s4 = 64 roots.
#define CH_THETA 46.0
#define CH_DELTA 45.0
#define NSTEP 64

#define NTHR 256

typedef float f4u __attribute__((ext_vector_type(4), aligned(4)));

__device__ __forceinline__ void diag4(int i, int t, float dg[4]) {
  bool im = (i > 0), ip = (i < GSZ - 1);
#pragma unroll
  for (int k = 0; k < 4; ++k) {
    bool jm = (k > 0) || (t > 0);
    bool jp = (k < 3) || (t < 255);
    int deg = (int)jm + (int)jp + (int)im + (int)ip
            + (int)(ip && jm) + (int)(im && jp);
    dg[k] = 1.0f + LAM * (float)deg;
  }
}

// q = (A x)_row for this thread's 4 cols (guards zero out-of-grid terms;
// self-healing trapezoid semantics validated r8-r13).
__device__ __forceinline__ void sten_q4(
    const float* up, const float* mid, const float* dn,
    float Lm, float Ld, float Rm, float Ru,
    int r, int t2, float q[4]) {
  bool im = (r > 0), ip = (r < GSZ - 1);
  bool jm = (t2 > 0), jp = (t2 < 255);
  float u0 = im ? up[0] : 0.f, u1 = im ? up[1] : 0.f;
  float u2 = im ? up[2] : 0.f, u3 = im ? up[3] : 0.f;
  float d0 = ip ? dn[0] : 0.f, d1 = ip ? dn[1] : 0.f;
  float d2 = ip ? dn[2] : 0.f, d3 = ip ? dn[3] : 0.f;
  float lm = jm ? Lm : 0.f, ld = (jm && ip) ? Ld : 0.f;
  float rm = jp ? Rm : 0.f, ru = (jp && im) ? Ru : 0.f;
  float dg[4]; diag4(r, t2, dg);
  q[0] = dg[0]*mid[0] - LAM*(lm     + mid[1] + u0 + d0 + ld + u1);
  q[1] = dg[1]*mid[1] - LAM*(mid[0] + mid[2] + u1 + d1 + d0 + u2);
  q[2] = dg[2]*mid[2] - LAM*(mid[1] + mid[3] + u2 + d2 + d1 + u3);
  q[3] = dg[3]*mid[3] - LAM*(mid[2] + rm     + u3 + d3 + d2 + ru);
}

// interleaved u -> one color's float4 at vtx..vtx+3
__device__ __forceinline__ float4 load_u_col(const float* __restrict__ u,
                                             int vtx, int col) {
  float4 a = *(const float4*)(u + 3 * vtx);
  float4 b = *(const float4*)(u + 3 * vtx + 4);
  float4 c = *(const float4*)(u + 3 * vtx + 8);
  if (col == 0) return make_float4(a.x, a.w, b.z, c.y);
  if (col == 1) return make_float4(a.y, b.x, b.w, c.z);
  return make_float4(a.z, b.y, c.x, c.w);
}

// One Richardson level, in-place on X, rows [LO,HI], tile offset OFF
// (grid row = r0 - OFF + tr). Edge exchange of OLD values -> shuffles ->
// rolling ascending update (validated r12/r13).
#define DO_LEVEL(LEV, LO, HI, OM, OFF)                                      \
  {                                                                         \
    if (lane == 0) {                                                        \
      _Pragma("unroll") for (int tr = (LO)-1; tr <= (HI)+1; ++tr)           \
        e0[LEV][wv][tr] = X[tr][0];                                         \
    }                                                                       \
    if (lane == 63) {                                                       \
      _Pragma("unroll") for (int tr = (LO)-1; tr <= (HI)+1; ++tr)           \
        e3[LEV][wv][tr] = X[tr][3];                                         \
    }                                                                       \
    __syncthreads();                                                        \
    float XL[12], XR[12];                                                   \
    _Pragma("unroll") for (int tr = (LO)-1; tr <= (HI)+1; ++tr) {           \
      XR[tr] = __shfl_down(X[tr][0], 1, 64);                                \
      XL[tr] = __shfl_up(X[tr][3], 1, 64);                                  \
    }                                                                       \
    if (lane == 63) {                                                       \
      _Pragma("unroll") for (int tr = (LO)-1; tr <= (HI)+1; ++tr)           \
        XR[tr] = (t2 < 255) ? e0[LEV][wv + 1][tr] : 0.f;                    \
    }                                                                       \
    if (lane == 0) {                                                        \
      _Pragma("unroll") for (int tr = (LO)-1; tr <= (HI)+1; ++tr)           \
        XL[tr] = (t2 > 0) ? e3[LEV][wv - 1][tr] : 0.f;                      \
    }                                                                       \
    float pm0 = X[(LO)-1][0], pm1 = X[(LO)-1][1],                           \
          pm2 = X[(LO)-1][2], pm3 = X[(LO)-1][3];                           \
    _Pragma("unroll") for (int tr = (LO); tr <= (HI); ++tr) {               \
      int r = r0 - (OFF) + tr;                                              \
      float pm[4] = { pm0, pm1, pm2, pm3 };                                 \
      float q[4];                                                           \
      sten_q4(pm, X[tr], X[tr+1], XL[tr], XL[tr+1], XR[tr], XR[tr-1],       \
              r, t2, q);                                                    \
      pm0 = X[tr][0]; pm1 = X[tr][1]; pm2 = X[tr][2]; pm3 = X[tr][3];       \
      _Pragma("unroll") for (int k = 0; k < 4; ++k)                         \
        X[tr][k] += (OM) * (BB[tr-1][k] - q[k]);                            \
    }                                                                       \
  }

// ---------- fused 3-step Richardson (r13 steady state, 11.5 us proven) ----------
// Reads x (stencil, 10 rows) + b (rows 1..8), writes x' rows 3..6.
__global__ __launch_bounds__(256, 3) void k_rich3(
    const float* __restrict__ xin, float* __restrict__ xout,
    const float* __restrict__ bpl,
    float w0, float w1, float w2) {
  int tile = blockIdx.x & 255;
  int col  = blockIdx.x >> 8;
  int t2 = threadIdx.x;
  int lane = t2 & 63;
  int wv = t2 >> 6;
  int r0 = ((tile & 7) << 7) + ((tile >> 3) << 2);   // output rows [r0, r0+4)
  int j0 = t2 << 2;

  const float* XS = xin + col * NV;
  const float* BP = bpl + col * NV;
  float* XO = xout + col * NV;

  __shared__ float e0[3][4][10], e3[3][4][10];

  float X[10][4];
#pragma unroll
  for (int tr = 0; tr < 10; ++tr) {
    int r = r0 - 3 + tr;
    if (r >= 0 && r < GSZ) {
      float4 v = *(const float4*)(XS + r * GSZ + j0);
      X[tr][0]=v.x; X[tr][1]=v.y; X[tr][2]=v.z; X[tr][3]=v.w;
    } else { X[tr][0]=0.f; X[tr][1]=0.f; X[tr][2]=0.f; X[tr][3]=0.f; }
  }
  float BB[8][4];
#pragma unroll
  for (int tr = 1; tr <= 8; ++tr) {
    int r = r0 - 3 + tr;
    if (r >= 0 && r < GSZ) {
      float4 v = *(const float4*)(BP + r * GSZ + j0);
      BB[tr-1][0]=v.x; BB[tr-1][1]=v.y; BB[tr-1][2]=v.z; BB[tr-1][3]=v.w;
    } else { BB[tr-1][0]=0.f; BB[tr-1][1]=0.f; BB[tr-1][2]=0.f; BB[tr-1][3]=0.f; }
  }

  DO_LEVEL(0, 1, 8, w0, 3)
  DO_LEVEL(1, 2, 7, w1, 3)
  DO_LEVEL(2, 3, 6, w2, 3)

#pragma unroll
  for (int tr = 3; tr <= 6; ++tr) {
    int r = r0 - 3 + tr;
    *(float4*)(XO + r * GSZ + j0) = make_float4(X[tr][0], X[tr][1], X[tr][2], X[tr][3]);
  }
}

// ---------- first launch: x=0; b from u (transposed); writes bpl rows 3..6 ----------
__global__ __launch_bounds__(256, 3) void k_rich3_first(
    const float* __restrict__ u, float* __restrict__ xout,
    float* __restrict__ bpl,
    float w0, float w1, float w2) {
  int tile = blockIdx.x & 255;
  int col  = blockIdx.x >> 8;
  int t2 = threadIdx.x;
  int lane = t2 & 63;
  int wv = t2 >> 6;
  int r0 = ((tile & 7) << 7) + ((tile >> 3) << 2);
  int j0 = t2 << 2;

  float* BPo = bpl + col * NV;
  float* XO  = xout + col * NV;

  __shared__ float e0[3][4][10], e3[3][4][10];

  float X[10][4];
#pragma unroll
  for (int tr = 0; tr < 10; ++tr) {
    X[tr][0]=0.f; X[tr][1]=0.f; X[tr][2]=0.f; X[tr][3]=0.f;
  }
  float BB[8][4];
#pragma unroll
  for (int tr = 1; tr <= 8; ++tr) {
    int r = r0 - 3 + tr;
    float4 v = (r >= 0 && r < GSZ) ? load_u_col(u, r * GSZ + j0, col)
                                   : make_float4(0.f, 0.f, 0.f, 0.f);
    BB[tr-1][0]=v.x; BB[tr-1][1]=v.y; BB[tr-1][2]=v.z; BB[tr-1][3]=v.w;
    if (tr >= 3 && tr <= 6)        // publish b for this block's output rows
      *(float4*)(BPo + r * GSZ + j0) = v;
  }

  DO_LEVEL(0, 1, 8, w0, 3)
  DO_LEVEL(1, 2, 7, w1, 3)
  DO_LEVEL(2, 3, 6, w2, 3)

#pragma unroll
  for (int tr = 3; tr <= 6; ++tr) {
    int r = r0 - 3 + tr;
    *(float4*)(XO + r * GSZ + j0) = make_float4(X[tr][0], X[tr][1], X[tr][2], X[tr][3]);
  }
}

// ---------- final fused 4-step (r12/r13 kernel, validated) ----------
__global__ __launch_bounds__(256, 3) void k_rich4(
    const float* __restrict__ xin, float* __restrict__ xout,
    const float* __restrict__ bpl,
    float w0, float w1, float w2, float w3) {
  int tile = blockIdx.x & 255;
  int col  = blockIdx.x >> 8;
  int t2 = threadIdx.x;
  int lane = t2 & 63;
  int wv = t2 >> 6;
  int r0 = ((tile & 7) << 7) + ((tile >> 3) << 2);
  int j0 = t2 << 2;

  const float* XS = xin + col * NV;
  const float* BP = bpl + col * NV;
  float* XO = xout + col * NV;

  __shared__ float e0[4][4][12], e3[4][4][12];

  float X[12][4];
#pragma unroll
  for (int tr = 0; tr < 12; ++tr) {
    int r = r0 - 4 + tr;
    if (r >= 0 && r < GSZ) {
      float4 v = *(const float4*)(XS + r * GSZ + j0);
      X[tr][0]=v.x; X[tr][1]=v.y; X[tr][2]=v.z; X[tr][3]=v.w;
    } else { X[tr][0]=0.f; X[tr][1]=0.f; X[tr][2]=0.f; X[tr][3]=0.f; }
  }
  float BB[10][4];
#pragma unroll
  for (int tr = 1; tr <= 10; ++tr) {
    int r = r0 - 4 + tr;
    if (r >= 0 && r < GSZ) {
      float4 v = *(const float4*)(BP + r * GSZ + j0);
      BB[tr-1][0]=v.x; BB[tr-1][1]=v.y; BB[tr-1][2]=v.z; BB[tr-1][3]=v.w;
    } else { BB[tr-1][0]=0.f; BB[tr-1][1]=0.f; BB[tr-1][2]=0.f; BB[tr-1][3]=0.f; }
  }

  DO_LEVEL(0, 1, 10, w0, 4)
  DO_LEVEL(1, 2,  9, w1, 4)
  DO_LEVEL(2, 3,  8, w2, 4)
  DO_LEVEL(3, 4,  7, w3, 4)

#pragma unroll
  for (int tr = 4; tr <= 7; ++tr) {
    int r = r0 - 4 + tr;
    *(float4*)(XO + r * GSZ + j0) = make_float4(X[tr][0], X[tr][1], X[tr][2], X[tr][3]);
  }
}

// ---------- faces + verts (validated rounds 10-15) ----------
__device__ __forceinline__ void face_cf(float t0x, float t0y, float t0z,
    float t1x, float t1y, float t1z, float b0x, float b0y, float b0z,
    float* cen, float* fnv) {
  const float third = 1.0f / 3.0f;
  cen[0] = (t0x + t1x + b0x) * third;
  cen[1] = (t0y + t1y + b0y) * third;
  cen[2] = (t0z + t1z + b0z) * third;
  float ax = t1x - t0x, ay = t1y - t0y, az = t1z - t0z;
  float bx = b0x - t0x, by = b0y - t0y, bz = b0z - t0z;
  float cx = ay * bz - az * by;
  float cy = az * bx - ax * bz;
  float cz = ax * by - ay * bx;
  float inv = 1.0f / fmaxf(sqrtf(cx * cx + cy * cy + cz * cz), 1e-12f);
  fnv[0] = cx * inv; fnv[1] = cy * inv; fnv[2] = cz * inv;
}

__global__ __launch_bounds__(NTHR) void k_facesverts(const float* __restrict__ xp,
    float* __restrict__ verts, float* __restrict__ cen, float* __restrict__ fn) {
  int ci = blockIdx.x;           // 0..1022
  int t  = threadIdx.x;
  const float* Ps[3] = { xp, xp + NV, xp + 2 * NV };
  int c0 = t << 2;
  int bT = (ci << 10) + c0, bB = bT + GSZ;
  bool full = (t < 255);
  float T[3][5], B[3][5];
#pragma unroll
  for (int p = 0; p < 3; ++p) {
    float4 a = *(const float4*)(Ps[p] + bT);
    T[p][0] = a.x; T[p][1] = a.y; T[p][2] = a.z; T[p][3] = a.w;
    T[p][4] = full ? Ps[p][bT + 4] : 0.f;
    float4 b = *(const float4*)(Ps[p] + bB);
    B[p][0] = b.x; B[p][1] = b.y; B[p][2] = b.z; B[p][3] = b.w;
    B[p][4] = full ? Ps[p][bB + 4] : 0.f;
  }
  {
    int vtx = bT;
    *(float4*)(verts + 3 * vtx)     = make_float4(T[0][0], T[1][0], T[2][0], T[0][1]);
    *(float4*)(verts + 3 * vtx + 4) = make_float4(T[1][1], T[2][1], T[0][2], T[1][2]);
    *(float4*)(verts + 3 * vtx + 8) = make_float4(T[2][2], T[0][3], T[1][3], T[2][3]);
    if (ci == GSZ - 2) {
      int v2 = bB;
      *(float4*)(verts + 3 * v2)     = make_float4(B[0][0], B[1][0], B[2][0], B[0][1]);
      *(float4*)(verts + 3 * v2 + 4) = make_float4(B[1][1], B[2][1], B[0][2], B[1][2]);
      *(float4*)(verts + 3 * v2 + 8) = make_float4(B[2][2], B[0][3], B[1][3], B[2][3]);
    }
  }
  float c1[12], f1[12], c2[12], f2[12];
#pragma unroll
  for (int k = 0; k < 4; ++k) {
    face_cf(T[0][k], T[1][k], T[2][k], T[0][k+1], T[1][k+1], T[2][k+1],
            B[0][k], B[1][k], B[2][k], &c1[3*k], &f1[3*k]);
    face_cf(T[0][k+1], T[1][k+1], T[2][k+1], B[0][k+1], B[1][k+1], B[2][k+1],
            B[0][k], B[1][k], B[2][k], &c2[3*k], &f2[3*k]);
  }
  size_t fb1 = 3 * ((size_t)ci * (GSZ - 1) + c0);
  size_t fb2 = fb1 + 3 * (size_t)FH;
  if (full) {
#pragma unroll
    for (int w = 0; w < 3; ++w) {
      *(f4u*)(cen + fb1 + 4*w) = (f4u){ c1[4*w], c1[4*w+1], c1[4*w+2], c1[4*w+3] };
      *(f4u*)(fn  + fb1 + 4*w) = (f4u){ f1[4*w], f1[4*w+1], f1[4*w+2], f1[4*w+3] };
      *(f4u*)(cen + fb2 + 4*w) = (f4u){ c2[4*w], c2[4*w+1], c2[4*w+2], c2[4*w+3] };
      *(f4u*)(fn  + fb2 + 4*w) = (f4u){ f2[4*w], f2[4*w+1], f2[4*w+2], f2[4*w+3] };
    }
  } else {
    for (int e = 0; e < 9; ++e) {
      cen[fb1 + e] = c1[e]; fn[fb1 + e] = f1[e];
      cen[fb2 + e] = c2[e]; fn[fb2 + e] = f2[e];
    }
  }
}

// ---------- per-vertex normal: vectorized fn gather (G13) ----------
// 4 vertices/thread. Face-cell segments (f1/f2 x rows i-1,i) loaded as
// 3x f4u (cells c0..c0+3) + 3 guarded scalars (cell c0-1). Sum order is
// term-for-term identical to the validated scalar k_vn -> bitwise-same vn.
// Right-edge f4u overreads (<=3 floats) land in adjacent valid regions and
// are guard-masked (cell 1023 never summed).
__global__ __launch_bounds__(256) void k_vn(const float* __restrict__ fn,
    float* __restrict__ vn) {
  int i = blockIdx.x;            // vertex row 0..1023
  int t = threadIdx.x;
  int c0 = t << 2;
  bool iN = (i >= 1), iS = (i <= GSZ - 2);
  const float* F1 = fn;
  const float* F2 = fn + 3 * (size_t)FH;

  float s1i[12], s2i[12], s1p[12], s2p[12];   // cells c0..c0+3, rows i / i-1
  float h1i[3], h2i[3], h1p[3], h2p[3];       // cell c0-1
  size_t rI = (size_t)i * (GSZ - 1);
  size_t rP = (size_t)(i - 1) * (GSZ - 1);
#define LOADSEG(dst, hd, base, valid)                                        \
  {                                                                          \
    if (valid) {                                                             \
      size_t f0 = 3 * ((base) + c0);                                         \
      *(f4u*)&dst[0] = *(const f4u*)(&fn[0] + f0);  /* placeholder */        \
    }                                                                        \
  }
#undef LOADSEG
  // f1 row i
  if (iS) {
    size_t f0 = 3 * (rI + c0);
    f4u a = *(const f4u*)(F1 + f0);
    f4u b = *(const f4u*)(F1 + f0 + 4);
    f4u c = *(const f4u*)(F1 + f0 + 8);
    s1i[0]=a.x; s1i[1]=a.y; s1i[2]=a.z; s1i[3]=a.w;
    s1i[4]=b.x; s1i[5]=b.y; s1i[6]=b.z; s1i[7]=b.w;
    s1i[8]=c.x; s1i[9]=c.y; s1i[10]=c.z; s1i[11]=c.w;
    if (t > 0) { h1i[0]=F1[f0-3]; h1i[1]=F1[f0-2]; h1i[2]=F1[f0-1]; }
    else       { h1i[0]=h1i[1]=h1i[2]=0.f; }
  } else {
#pragma unroll
    for (int e = 0; e < 12; ++e) s1i[e] = 0.f;
    h1i[0]=h1i[1]=h1i[2]=0.f;
  }
  // f2 row i
  if (iS) {
    size_t f0 = 3 * (rI + c0);
    f4u a = *(const f4u*)(F2 + f0);
    f4u b = *(const f4u*)(F2 + f0 + 4);
    f4u c = *(const f4u*)(F2 + f0 + 8);
    s2i[0]=a.x; s2i[1]=a.y; s2i[2]=a.z; s2i[3]=a.w;
    s2i[4]=b.x; s2i[5]=b.y; s2i[6]=b.z; s2i[7]=b.w;
    s2i[8]=c.x; s2i[9]=c.y; s2i[10]=c.z; s2i[11]=c.w;
    if (t > 0) { h2i[0]=F2[f0-3]; h2i[1]=F2[f0-2]; h2i[2]=F2[f0-1]; }
    else       { h2i[0]=h2i[1]=h2i[2]=0.f; }
  } else {
#pragma unroll
    for (int e = 0; e < 12; ++e) s2i[e] = 0.f;
    h2i[0]=h2i[1]=h2i[2]=0.f;
  }
  // f1 row i-1
  if (iN) {
    size_t f0 = 3 * (rP + c0);
    f4u a = *(const f4u*)(F1 + f0);
    f4u b = *(const f4u*)(F1 + f0 + 4);
    f4u c = *(const f4u*)(F1 + f0 + 8);
    s1p[0]=a.x; s1p[1]=a.y; s1p[2]=a.z; s1p[3]=a.w;
    s1p[4]=b.x; s1p[5]=b.y; s1p[6]=b.z; s1p[7]=b.w;
    s1p[8]=c.x; s1p[9]=c.y; s1p[10]=c.z; s1p[11]=c.w;
    if (t > 0) { h1p[0]=F1[f0-3]; h1p[1]=F1[f0-2]; h1p[2]=F1[f0-1]; }
    else       { h1p[0]=h1p[1]=h1p[2]=0.f; }
  } else {
#pragma unroll
    for (int e = 0; e < 12; ++e) s1p[e] = 0.f;
    h1p[0]=h1p[1]=h1p[2]=0.f;
  }
  // f2 row i-1
  if (iN) {
    size_t f0 = 3 * (rP + c0);
    f4u a = *(const f4u*)(F2 + f0);
    f4u b = *(const f4u*)(F2 + f0 + 4);
    f4u c = *(const f4u*)(F2 + f0 + 8);
    s2p[0]=a.x; s2p[1]=a.y; s2p[2]=a.z; s2p[3]=a.w;
    s2p[4]=b.x; s2p[5]=b.y; s2p[6]=b.z; s2p[7]=b.w;
    s2p[8]=c.x; s2p[9]=c.y; s2p[10]=c.z; s2p[11]=c.w;
    if (t > 0) { h2p[0]=F2[f0-3]; h2p[1]=F2[f0-2]; h2p[2]=F2[f0-1]; }
    else       { h2p[0]=h2p[1]=h2p[2]=0.f; }
  } else {
#pragma unroll
    for (int e = 0; e < 12; ++e) s2p[e] = 0.f;
    h2p[0]=h2p[1]=h2p[2]=0.f;
  }

  float outv[12];
#pragma unroll
  for (int k = 0; k < 4; ++k) {
    int j = c0 + k;
    bool jW = (j >= 1);                      // k>0 always true; k==0: t>0
    bool jE = (j <= GSZ - 2);                // k<3 always true; k==3: t<255
    float s0 = 0.f, s1 = 0.f, s2 = 0.f;
    // order matches validated scalar k_vn exactly:
    if (iS && jE) { s0 += s1i[3*k];   s1 += s1i[3*k+1];   s2 += s1i[3*k+2]; }
    if (iS && jW) {
      float a0 = (k>0)? s1i[3*(k-1)]   : h1i[0];
      float a1 = (k>0)? s1i[3*(k-1)+1] : h1i[1];
      float a2 = (k>0)? s1i[3*(k-1)+2] : h1i[2];
      s0 += a0; s1 += a1; s2 += a2;
    }
    if (iN && jE) { s0 += s1p[3*k];   s1 += s1p[3*k+1];   s2 += s1p[3*k+2]; }
    if (iS && jW) {
      float a0 = (k>0)? s2i[3*(k-1)]   : h2i[0];
      float a1 = (k>0)? s2i[3*(k-1)+1] : h2i[1];
      float a2 = (k>0)? s2i[3*(k-1)+2] : h2i[2];
      s0 += a0; s1 += a1; s2 += a2;
    }
    if (iN && jW) {
      float a0 = (k>0)? s2p[3*(k-1)]   : h2p[0];
      float a1 = (k>0)? s2p[3*(k-1)+1] : h2p[1];
      float a2 = (k>0)? s2p[3*(k-1)+2] : h2p[2];
      s0 += a0; s1 += a1; s2 += a2;
    }
    if (iN && jE) { s0 += s2p[3*k];   s1 += s2p[3*k+1];   s2 += s2p[3*k+2]; }
    float nrm = sqrtf(s0*s0 + s1*s1 + s2*s2);
    float inv = 1.0f / fmaxf(nrm, 1e-12f);
    outv[3*k] = s0*inv; outv[3*k+1] = s1*inv; outv[3*k+2] = s2*inv;
  }
  size_t vb = 3 * ((size_t)i * GSZ + c0);
#pragma unroll
  for (int w = 0; w < 3; ++w)
    *(f4u*)(vn + vb + 4*w) = (f4u){ outv[4*w], outv[4*w+1], outv[4*w+2], outv[4*w+3] };
}

extern "C" void kernel_launch(void* const* d_in, const int* in_sizes, int n_in,
                              void* d_out, int out_size, void* d_ws, size_t ws_size,
                              hipStream_t stream) {
  const float* u = (const float*)d_in[0];
  float* out = (float*)d_out;

  float* verts = out;
  float* cen   = out + O1;
  float* fn    = out + O2;
  float* vn    = out + O3;

  // Scratch: XA = verts region, bpl + XB inside cen/fn region (6NV < 6NF),
  // Dv = vn region (final x; k_vn overwrites last).
  float* XA  = out;
  float* bpl = out + O1;
  float* XB  = out + O1 + 3 * (size_t)NV;
  float* Dv  = out + O3;

  // Lebedev-Finogenov ordering of the 64 Chebyshev roots (doubling).
  int ord[64]; ord[0] = 1;
  for (int m = 1; m < 64; m *= 2) {
    int tmp[128];
    for (int i = 0; i < m; ++i) { tmp[2*i] = ord[i]; tmp[2*i+1] = 4*m - ord[i]; }
    for (int i = 0; i < 2*m; ++i) ord[i] = tmp[i];
  }
  float om[NSTEP];
  for (int j = 0; j < NSTEP; ++j) {
    double r = CH_THETA + CH_DELTA * cos((double)ord[j] * M_PI / (2.0 * NSTEP));
    om[j] = (float)(1.0 / r);
  }

  // 21 launches (r13 schedule): j=0 rich3_first (roots 0..2), j=1..19 rich3
  // (roots 3j..3j+2), j=20 rich4 (roots 60..63).
  // Parity: j even writes XA, odd writes XB; j=19 wrote XB; j=20 XB -> Dv.
  for (int j = 0; j < 21; ++j) {
    if (j == 0) {
      k_rich3_first<<<dim3(768), dim3(256), 0, stream>>>(u, XA, bpl,
          om[0], om[1], om[2]);
    } else if (j < 20) {
      const float* xin = (j & 1) ? XA : XB;
      float* xout = (j & 1) ? XB : XA;
      k_rich3<<<dim3(768), dim3(256), 0, stream>>>(xin, xout, bpl,
          om[3*j], om[3*j+1], om[3*j+2]);
    } else {
      k_rich4<<<dim3(768), dim3(256), 0, stream>>>(XB, Dv, bpl,
          om[60], om[61], om[62], om[63]);
    }
  }

  k_facesverts<<<dim3(GSZ - 1), dim3(NTHR), 0, stream>>>(Dv, verts, cen, fn);
  k_vn<<<dim3(GSZ), dim3(256), 0, stream>>>(fn, vn);
}